// Round 6
// baseline (306.199 us; speedup 1.0000x reference)
//
#include <hip/hip_runtime.h>

typedef _Float16 f16x8 __attribute__((ext_vector_type(8)));
typedef _Float16 f16x4 __attribute__((ext_vector_type(4)));
typedef float f32x4 __attribute__((ext_vector_type(4)));

#define NH 12
#define SEQ 2048
#define DM 768
#define DH 64

// pb LDS address: [row 0..63][byte 0..1023], XOR-swizzled so that
// (a) 16-row strided b64 reads spread across bank-quads and
// (b) staging b128 writes from 4 same-row threads spread across slots.
#define SWZB(row, bo) ((row) * 1024 + ((bo) ^ (((row) & 7) << 4) ^ ((((bo) >> 8) & 3) << 4)))

// ---------------- cast fp32 -> fp16 (X and the 4 weight matrices) --------
__global__ __launch_bounds__(256) void cast_kernel(
    const float* __restrict__ X, const float* __restrict__ Wq,
    const float* __restrict__ Wk, const float* __restrict__ Wv,
    const float* __restrict__ Wo, _Float16* __restrict__ Xh,
    _Float16* __restrict__ Wall)
{
    size_t base = ((size_t)blockIdx.x * 256 + threadIdx.x) * 8;
    const size_t NX = 3145728, NW = 589824, TOT = NX + 4 * NW;
    if (base >= TOT) return;
    const float* src;
    _Float16* dst;
    if (base < NX) { src = X + base; dst = Xh + base; }
    else {
        size_t r = base - NX;
        int w = (int)(r / NW);
        size_t o = r - (size_t)w * NW;
        src = (w == 0 ? Wq : w == 1 ? Wk : w == 2 ? Wv : Wo) + o;
        dst = Wall + r;
    }
    float4 a = *reinterpret_cast<const float4*>(src);
    float4 b = *reinterpret_cast<const float4*>(src + 4);
    f16x8 h;
    h[0] = (_Float16)a.x; h[1] = (_Float16)a.y; h[2] = (_Float16)a.z; h[3] = (_Float16)a.w;
    h[4] = (_Float16)b.x; h[5] = (_Float16)b.y; h[6] = (_Float16)b.z; h[7] = (_Float16)b.w;
    *reinterpret_cast<f16x8*>(dst) = h;
}

// ---------------- GEMM: out = A[4096x768] @ W^T + bias ------------------
// z=0 -> Q slab, z=1 -> K slab ([b,h,s,d]); z=2 -> V^T ([b,h,d,s]).
// is_out==1: fp32 d_out + bias.
__global__ __launch_bounds__(256) void gemm_kernel(
    const _Float16* __restrict__ A,
    const _Float16* __restrict__ Wbase,
    const float* __restrict__ b0, const float* __restrict__ b1,
    const float* __restrict__ b2,
    _Float16* __restrict__ outQKV, _Float16* __restrict__ outVT,
    float* __restrict__ outF32, int is_out)
{
    __shared__ _Float16 Asm[128 * 64];
    __shared__ _Float16 Bsm[128 * 64];
    const int tid = threadIdx.x;
    const int m0 = blockIdx.x * 128, n0 = blockIdx.y * 128, z = blockIdx.z;
    const _Float16* Wp = Wbase + (size_t)z * 589824;
    const float* bias = (z == 0) ? b0 : (z == 1 ? b1 : b2);
    const int w = tid >> 6, lane = tid & 63, lr = lane & 15, lg = lane >> 4;
    const int wm = w >> 1, wn = w & 1;

    f32x4 acc[4][4] = {};
    for (int kt = 0; kt < 12; ++kt) {
        __syncthreads();
        #pragma unroll
        for (int i = 0; i < 4; ++i) {
            int c = tid + i * 256;
            int row = c >> 3, col = (c & 7) * 8;
            int sw = (row & 7) << 4;
            f16x8 av = *reinterpret_cast<const f16x8*>(A + (size_t)(m0 + row) * 768 + kt * 64 + col);
            *reinterpret_cast<f16x8*>((char*)Asm + ((row * 128 + col * 2) ^ sw)) = av;
            f16x8 bv = *reinterpret_cast<const f16x8*>(Wp + (size_t)(n0 + row) * 768 + kt * 64 + col);
            *reinterpret_cast<f16x8*>((char*)Bsm + ((row * 128 + col * 2) ^ sw)) = bv;
        }
        __syncthreads();
        #pragma unroll
        for (int kf = 0; kf < 2; ++kf) {
            f16x8 af[4], bf[4];
            #pragma unroll
            for (int mi = 0; mi < 4; ++mi) {
                int row = wm * 64 + mi * 16 + lr;
                af[mi] = *reinterpret_cast<const f16x8*>(
                    (char*)Asm + ((row * 128 + kf * 64 + lg * 16) ^ ((row & 7) << 4)));
            }
            #pragma unroll
            for (int nj = 0; nj < 4; ++nj) {
                int row = wn * 64 + nj * 16 + lr;
                bf[nj] = *reinterpret_cast<const f16x8*>(
                    (char*)Bsm + ((row * 128 + kf * 64 + lg * 16) ^ ((row & 7) << 4)));
            }
            #pragma unroll
            for (int mi = 0; mi < 4; ++mi)
                #pragma unroll
                for (int nj = 0; nj < 4; ++nj)
                    acc[mi][nj] = __builtin_amdgcn_mfma_f32_16x16x32_f16(
                        af[mi], bf[nj], acc[mi][nj], 0, 0, 0);
        }
    }
    #pragma unroll
    for (int mi = 0; mi < 4; ++mi) {
        #pragma unroll
        for (int nj = 0; nj < 4; ++nj) {
            #pragma unroll
            for (int r = 0; r < 4; ++r) {
                int gm = m0 + wm * 64 + mi * 16 + lg * 4 + r;
                int gn = n0 + wn * 64 + nj * 16 + lr;
                float v = acc[mi][nj][r] + bias[gn];
                if (!is_out) {
                    int bb = gm >> 11, s = gm & 2047, hh = gn >> 6, dd = gn & 63;
                    if (z == 2)
                        outVT[(((size_t)bb * NH + hh) * DH + dd) * SEQ + s] = (_Float16)v;
                    else
                        outQKV[(size_t)z * 3145728 +
                               ((((size_t)bb * NH + hh) * SEQ + s) * DH + dd)] = (_Float16)v;
                } else {
                    outF32[(size_t)gm * 768 + gn] = v;
                }
            }
        }
    }
}

// ---------------- flash attention with pb superstep staging --------------
// Block = (b, h, 64 q-rows). 4 waves; wave w owns q-rows [w*16, w*16+16).
// pb is staged per 512-kt superstep into a 64KB fp16 LDS tile via coarse
// (2KB/row) sequential reads — this is the HBM-efficiency lever. K/V frags
// are loaded directly from global (L1/L2-hot); no per-iteration barriers.
__global__ __launch_bounds__(256, 2) void attn_kernel(
    const _Float16* __restrict__ Qh, const _Float16* __restrict__ Kh,
    const _Float16* __restrict__ VTg, const float* __restrict__ pb,
    const float* __restrict__ mask, _Float16* __restrict__ ctx)
{
    __shared__ _Float16 pbL[64 * 512];    // 64KB, (pb+...)*log2e in fp16
    __shared__ _Float16 Pl[4 * 16 * 64];  // 8KB, per-wave P tiles
    const int tid = threadIdx.x, w = tid >> 6, lane = tid & 63;
    const int lr = lane & 15, lg = lane >> 4;
    // XCD-aware decode: 768 blocks = 8 XCD * (3 bh * 32 q0)
    const int lin = blockIdx.x;
    const int xcd = lin & 7, idx = lin >> 3;        // idx in [0,96)
    const int bh = xcd * 3 + idx / 32;
    const int q0 = (idx & 31) << 6;
    const int h = bh % NH, b = bh / NH;
    const size_t headoff = (size_t)bh * SEQ * DH;
    const _Float16* Qp = Qh + headoff;
    const _Float16* Kp = Kh + headoff;
    const _Float16* VTp = VTg + headoff;            // [d][s] per head
    const float L2E = 1.44269504f;

    // Q B-frags (q = lr within the wave's 16 rows)
    f16x8 qfr[2];
    #pragma unroll
    for (int kf = 0; kf < 2; ++kf)
        qfr[kf] = *reinterpret_cast<const f16x8*>(
            Qp + (size_t)(q0 + w * 16 + lr) * DH + kf * 32 + lg * 8);

    // staging geometry: thread -> (row, 128-col chunk)
    const int srow = tid >> 2;
    const int scol = (tid & 3) * 128;
    const float* psrc = pb + (size_t)h * SEQ * SEQ + (size_t)(q0 + srow) * SEQ + scol;
    const float* mrow = mask + (size_t)b * SEQ;

    f32x4 oacc[4] = {};
    float m_r = -3.0e38f, l_r = 0.f;
    char* pbB = (char*)pbL;
    char* Pw = (char*)Pl + w * 2048;

    for (int ss = 0; ss < 4; ++ss) {
        __syncthreads();   // all waves done reading previous superstep's pbL
        // ---- stage pb[64][512] fp32 -> fp16*log2e, coarse sequential ----
        {
            const float* s0 = psrc + ss * 512;
            f32x4 ca = *(const f32x4*)(s0 + 0);
            f32x4 cb = *(const f32x4*)(s0 + 4);
            f32x4 cc = *(const f32x4*)(s0 + 8);
            f32x4 cd = *(const f32x4*)(s0 + 12);
            #pragma unroll
            for (int j = 0; j < 8; ++j) {
                f32x4 na = {}, nb = {}, nc = {}, nd = {};
                if (j < 7) {
                    const float* sj = s0 + (j + 1) * 16;
                    na = *(const f32x4*)(sj + 0);
                    nb = *(const f32x4*)(sj + 4);
                    nc = *(const f32x4*)(sj + 8);
                    nd = *(const f32x4*)(sj + 12);
                }
                f16x8 lo, hi;
                #pragma unroll
                for (int i = 0; i < 4; ++i) {
                    lo[i]     = (_Float16)(ca[i] * L2E);
                    lo[4 + i] = (_Float16)(cb[i] * L2E);
                    hi[i]     = (_Float16)(cc[i] * L2E);
                    hi[4 + i] = (_Float16)(cd[i] * L2E);
                }
                int bo = (scol + j * 16) * 2;
                *reinterpret_cast<f16x8*>(pbB + SWZB(srow, bo)) = lo;
                *reinterpret_cast<f16x8*>(pbB + SWZB(srow, bo + 16)) = hi;
                ca = na; cb = nb; cc = nc; cd = nd;
            }
        }
        __syncthreads();

        // ---- 8 iterations of 64 kt, barrier-free ----
        for (int it = 0; it < 8; ++it) {
            const int ktl = it * 64;
            const int ktg = ss * 512 + ktl;

            // K frags direct from global (L1/L2-hot), swapped QK^T: S[kt][q]
            f16x8 ka[4][2];
            #pragma unroll
            for (int cf = 0; cf < 4; ++cf)
                #pragma unroll
                for (int kf = 0; kf < 2; ++kf)
                    ka[cf][kf] = *reinterpret_cast<const f16x8*>(
                        Kp + (size_t)(ktg + cf * 16 + lr) * DH + kf * 32 + lg * 8);
            f32x4 sc[4] = {};
            #pragma unroll
            for (int cf = 0; cf < 4; ++cf)
                #pragma unroll
                for (int kf = 0; kf < 2; ++kf)
                    sc[cf] = __builtin_amdgcn_mfma_f32_16x16x32_f16(
                        ka[cf][kf], qfr[kf], sc[cf], 0, 0, 0);

            // sv = sc*scale*log2e + pbL + mask*log2e  (exp2 domain)
            // NOTE: pbL row is the BLOCK-local q-row = w*16 + lr (r5 bug: lr only)
            float sv[4][4];
            #pragma unroll
            for (int cf = 0; cf < 4; ++cf) {
                f16x4 pq = *reinterpret_cast<const f16x4*>(
                    pbB + SWZB(w * 16 + lr, (ktl + cf * 16 + lg * 4) * 2));
                f32x4 mk = *(const f32x4*)(mrow + ktg + cf * 16 + lg * 4);
                #pragma unroll
                for (int r = 0; r < 4; ++r)
                    sv[cf][r] = sc[cf][r] * 0.18033688f + (float)pq[r] + mk[r] * L2E;
            }

            // online softmax: q-row lr lane-local over 16 values, xor 16/32
            float t = sv[0][0];
            #pragma unroll
            for (int cf = 0; cf < 4; ++cf)
                #pragma unroll
                for (int r = 0; r < 4; ++r) t = fmaxf(t, sv[cf][r]);
            t = fmaxf(t, __shfl_xor(t, 16));
            t = fmaxf(t, __shfl_xor(t, 32));
            float mn = fmaxf(m_r, t);
            float sscale = exp2f(m_r - mn);
            m_r = mn;
            float rs = 0.f;
            #pragma unroll
            for (int cf = 0; cf < 4; ++cf) {
                f16x4 pv;
                #pragma unroll
                for (int r = 0; r < 4; ++r) {
                    float p = exp2f(sv[cf][r] - mn);
                    rs += p;
                    pv[r] = (_Float16)p;
                }
                *reinterpret_cast<f16x4*>(
                    Pw + ((lr * 128 + cf * 32 + lg * 8) ^ ((lr & 7) << 4))) = pv;
            }
            rs += __shfl_xor(rs, 16);
            rs += __shfl_xor(rs, 32);
            l_r = l_r * sscale + rs;
            f32x4 scv = {__shfl(sscale, lg * 4 + 0), __shfl(sscale, lg * 4 + 1),
                         __shfl(sscale, lg * 4 + 2), __shfl(sscale, lg * 4 + 3)};
            #pragma unroll
            for (int cf = 0; cf < 4; ++cf) oacc[cf] *= scv;

            // PV: A = P (wave-private LDS round-trip), B = V^T direct
            #pragma unroll
            for (int kf = 0; kf < 2; ++kf) {
                f16x8 pa = *reinterpret_cast<const f16x8*>(
                    Pw + ((lr * 128 + kf * 64 + lg * 16) ^ ((lr & 7) << 4)));
                #pragma unroll
                for (int cf = 0; cf < 4; ++cf) {
                    f16x8 vb = *reinterpret_cast<const f16x8*>(
                        VTp + (size_t)(cf * 16 + lr) * SEQ + ktg + kf * 32 + lg * 8);
                    oacc[cf] = __builtin_amdgcn_mfma_f32_16x16x32_f16(
                        pa, vb, oacc[cf], 0, 0, 0);
                }
            }
        }
    }

    // epilogue: normalize and write ctx[b, s, h*64+d] fp16
    float linv = 1.0f / l_r;
    f32x4 iv = {__shfl(linv, lg * 4 + 0), __shfl(linv, lg * 4 + 1),
                __shfl(linv, lg * 4 + 2), __shfl(linv, lg * 4 + 3)};
    #pragma unroll
    for (int r = 0; r < 4; ++r) {
        int grow = q0 + w * 16 + lg * 4 + r;
        #pragma unroll
        for (int cf = 0; cf < 4; ++cf)
            ctx[((size_t)b * SEQ + grow) * DM + h * DH + cf * 16 + lr] =
                (_Float16)(oacc[cf][r] * iv[r]);
    }
}

extern "C" void kernel_launch(void* const* d_in, const int* in_sizes, int n_in,
                              void* d_out, int out_size, void* d_ws, size_t ws_size,
                              hipStream_t stream) {
    const float* X    = (const float*)d_in[0];
    const float* mask = (const float*)d_in[1];
    const float* pb   = (const float*)d_in[2];
    const float* Wq   = (const float*)d_in[3];
    const float* bq   = (const float*)d_in[4];
    const float* Wk   = (const float*)d_in[5];
    const float* bk   = (const float*)d_in[6];
    const float* Wv   = (const float*)d_in[7];
    const float* bv   = (const float*)d_in[8];
    const float* Wo   = (const float*)d_in[9];
    const float* bo   = (const float*)d_in[10];
    float* out = (float*)d_out;

    _Float16* Xh   = (_Float16*)d_ws;              // 3145728 f16
    _Float16* Wall = Xh + 3145728;                 // 4 * 589824 f16
    _Float16* QK   = Wall + 4 * 589824;            // Q,K slabs: 2 * 3145728
    _Float16* VT   = QK + 2 * 3145728;             // V^T: 3145728
    _Float16* ctx  = VT + 3145728;                 // 3145728

    cast_kernel<<<2688, 256, 0, stream>>>(X, Wq, Wk, Wv, Wo, Xh, Wall);
    gemm_kernel<<<dim3(32, 6, 3), 256, 0, stream>>>(
        Xh, Wall, bq, bk, bv, QK, VT, nullptr, 0);
    attn_kernel<<<768, 256, 0, stream>>>(
        QK, QK + 3145728, VT, pb, mask, ctx);
    gemm_kernel<<<dim3(32, 6, 1), 256, 0, stream>>>(
        ctx, Wall + 3 * 589824, bo, bo, bo, nullptr, nullptr, out, 1);
}

// Round 7
// 287.155 us; speedup vs baseline: 1.0663x; 1.0663x over previous
//
#include <hip/hip_runtime.h>

typedef _Float16 f16x8 __attribute__((ext_vector_type(8)));
typedef _Float16 f16x4 __attribute__((ext_vector_type(4)));
typedef float f32x4 __attribute__((ext_vector_type(4)));

#define NH 12
#define SEQ 2048
#define DM 768
#define DH 64

// pb LDS: [row 0..63][byte 0..511] (fp16, 256 cols per superstep).
// XOR (row&7)<<4 spreads the 16-row-strided reads; 2-way worst case.
#define SWZB(row, bo) ((row) * 512 + ((bo) ^ (((row) & 7) << 4)))

// ---------------- cast fp32 -> fp16 (X and the 4 weight matrices) --------
__global__ __launch_bounds__(256) void cast_kernel(
    const float* __restrict__ X, const float* __restrict__ Wq,
    const float* __restrict__ Wk, const float* __restrict__ Wv,
    const float* __restrict__ Wo, _Float16* __restrict__ Xh,
    _Float16* __restrict__ Wall)
{
    size_t base = ((size_t)blockIdx.x * 256 + threadIdx.x) * 8;
    const size_t NX = 3145728, NW = 589824, TOT = NX + 4 * NW;
    if (base >= TOT) return;
    const float* src;
    _Float16* dst;
    if (base < NX) { src = X + base; dst = Xh + base; }
    else {
        size_t r = base - NX;
        int w = (int)(r / NW);
        size_t o = r - (size_t)w * NW;
        src = (w == 0 ? Wq : w == 1 ? Wk : w == 2 ? Wv : Wo) + o;
        dst = Wall + r;
    }
    float4 a = *reinterpret_cast<const float4*>(src);
    float4 b = *reinterpret_cast<const float4*>(src + 4);
    f16x8 h;
    h[0] = (_Float16)a.x; h[1] = (_Float16)a.y; h[2] = (_Float16)a.z; h[3] = (_Float16)a.w;
    h[4] = (_Float16)b.x; h[5] = (_Float16)b.y; h[6] = (_Float16)b.z; h[7] = (_Float16)b.w;
    *reinterpret_cast<f16x8*>(dst) = h;
}

// ---------------- GEMM: out = A[4096x768] @ W^T + bias ------------------
// z=0 -> Q slab, z=1 -> K slab ([b,h,s,d]); z=2 -> V^T ([b,h,d,s]).
// is_out==1: fp32 d_out + bias.
__global__ __launch_bounds__(256) void gemm_kernel(
    const _Float16* __restrict__ A,
    const _Float16* __restrict__ Wbase,
    const float* __restrict__ b0, const float* __restrict__ b1,
    const float* __restrict__ b2,
    _Float16* __restrict__ outQKV, _Float16* __restrict__ outVT,
    float* __restrict__ outF32, int is_out)
{
    __shared__ _Float16 Asm[128 * 64];
    __shared__ _Float16 Bsm[128 * 64];
    const int tid = threadIdx.x;
    const int m0 = blockIdx.x * 128, n0 = blockIdx.y * 128, z = blockIdx.z;
    const _Float16* Wp = Wbase + (size_t)z * 589824;
    const float* bias = (z == 0) ? b0 : (z == 1 ? b1 : b2);
    const int w = tid >> 6, lane = tid & 63, lr = lane & 15, lg = lane >> 4;
    const int wm = w >> 1, wn = w & 1;

    f32x4 acc[4][4] = {};
    for (int kt = 0; kt < 12; ++kt) {
        __syncthreads();
        #pragma unroll
        for (int i = 0; i < 4; ++i) {
            int c = tid + i * 256;
            int row = c >> 3, col = (c & 7) * 8;
            int sw = (row & 7) << 4;
            f16x8 av = *reinterpret_cast<const f16x8*>(A + (size_t)(m0 + row) * 768 + kt * 64 + col);
            *reinterpret_cast<f16x8*>((char*)Asm + ((row * 128 + col * 2) ^ sw)) = av;
            f16x8 bv = *reinterpret_cast<const f16x8*>(Wp + (size_t)(n0 + row) * 768 + kt * 64 + col);
            *reinterpret_cast<f16x8*>((char*)Bsm + ((row * 128 + col * 2) ^ sw)) = bv;
        }
        __syncthreads();
        #pragma unroll
        for (int kf = 0; kf < 2; ++kf) {
            f16x8 af[4], bf[4];
            #pragma unroll
            for (int mi = 0; mi < 4; ++mi) {
                int row = wm * 64 + mi * 16 + lr;
                af[mi] = *reinterpret_cast<const f16x8*>(
                    (char*)Asm + ((row * 128 + kf * 64 + lg * 16) ^ ((row & 7) << 4)));
            }
            #pragma unroll
            for (int nj = 0; nj < 4; ++nj) {
                int row = wn * 64 + nj * 16 + lr;
                bf[nj] = *reinterpret_cast<const f16x8*>(
                    (char*)Bsm + ((row * 128 + kf * 64 + lg * 16) ^ ((row & 7) << 4)));
            }
            #pragma unroll
            for (int mi = 0; mi < 4; ++mi)
                #pragma unroll
                for (int nj = 0; nj < 4; ++nj)
                    acc[mi][nj] = __builtin_amdgcn_mfma_f32_16x16x32_f16(
                        af[mi], bf[nj], acc[mi][nj], 0, 0, 0);
        }
    }
    #pragma unroll
    for (int mi = 0; mi < 4; ++mi) {
        #pragma unroll
        for (int nj = 0; nj < 4; ++nj) {
            #pragma unroll
            for (int r = 0; r < 4; ++r) {
                int gm = m0 + wm * 64 + mi * 16 + lg * 4 + r;
                int gn = n0 + wn * 64 + nj * 16 + lr;
                float v = acc[mi][nj][r] + bias[gn];
                if (!is_out) {
                    int bb = gm >> 11, s = gm & 2047, hh = gn >> 6, dd = gn & 63;
                    if (z == 2)
                        outVT[(((size_t)bb * NH + hh) * DH + dd) * SEQ + s] = (_Float16)v;
                    else
                        outQKV[(size_t)z * 3145728 +
                               ((((size_t)bb * NH + hh) * SEQ + s) * DH + dd)] = (_Float16)v;
                } else {
                    outF32[(size_t)gm * 768 + gn] = v;
                }
            }
        }
    }
}

// ---------------- flash attention with wave-contiguous pb staging --------
// Block = (b, h, 64 q-rows). 4 waves; wave w owns q-rows [w*16, w*16+16).
// Superstep = 256 kt: wave w stages pb rows [16w,16w+16) x 256 cols with
// 16 fully-coalesced 1KB-contiguous wave loads (one per row, 8 in flight),
// fp32 -> fp16*log2e into a 32KB swizzled LDS tile. 4 inner iterations per
// superstep read pb from LDS; K/V frags direct from global (L1/L2-hot).
__global__ __launch_bounds__(256, 3) void attn_kernel(
    const _Float16* __restrict__ Qh, const _Float16* __restrict__ Kh,
    const _Float16* __restrict__ VTg, const float* __restrict__ pb,
    const float* __restrict__ mask, _Float16* __restrict__ ctx)
{
    __shared__ _Float16 pbL[64 * 256];    // 32KB, (pb)*log2e in fp16
    __shared__ _Float16 Pl[4 * 16 * 64];  // 8KB, per-wave P tiles
    const int tid = threadIdx.x, w = tid >> 6, lane = tid & 63;
    const int lr = lane & 15, lg = lane >> 4;
    // XCD-aware decode: 768 blocks = 8 XCD * (3 bh * 32 q0)
    const int lin = blockIdx.x;
    const int xcd = lin & 7, idx = lin >> 3;        // idx in [0,96)
    const int bh = xcd * 3 + idx / 32;
    const int q0 = (idx & 31) << 6;
    const int h = bh % NH, b = bh / NH;
    const size_t headoff = (size_t)bh * SEQ * DH;
    const _Float16* Qp = Qh + headoff;
    const _Float16* Kp = Kh + headoff;
    const _Float16* VTp = VTg + headoff;            // [d][s] per head
    const float L2E = 1.44269504f;

    // Q B-frags (q = lr within the wave's 16 rows)
    f16x8 qfr[2];
    #pragma unroll
    for (int kf = 0; kf < 2; ++kf)
        qfr[kf] = *reinterpret_cast<const f16x8*>(
            Qp + (size_t)(q0 + w * 16 + lr) * DH + kf * 32 + lg * 8);

    // staging: wave w covers pb rows [q0+16w, q0+16w+16)
    const float* pwave = pb + (size_t)h * SEQ * SEQ + (size_t)(q0 + w * 16) * SEQ;
    const float* mrow = mask + (size_t)b * SEQ;

    f32x4 oacc[4] = {};
    float m_r = -3.0e38f, l_r = 0.f;
    char* pbB = (char*)pbL;
    char* Pw = (char*)Pl + w * 2048;

    for (int ss = 0; ss < 8; ++ss) {
        __syncthreads();   // all waves done reading previous superstep's pbL
        // ---- stage pb[64][256] fp32 -> fp16*log2e ----
        // one wave instruction = one row's 256 floats = 1KB contiguous.
        #pragma unroll
        for (int bsub = 0; bsub < 2; ++bsub) {
            f32x4 t[8];
            #pragma unroll
            for (int j = 0; j < 8; ++j) {
                int row = bsub * 8 + j;
                t[j] = *reinterpret_cast<const f32x4*>(
                    pwave + (size_t)row * SEQ + ss * 256 + 4 * lane);
            }
            #pragma unroll
            for (int j = 0; j < 8; ++j) {
                int row = bsub * 8 + j;
                f16x4 hv;
                #pragma unroll
                for (int i = 0; i < 4; ++i) hv[i] = (_Float16)(t[j][i] * L2E);
                *reinterpret_cast<f16x4*>(
                    pbB + SWZB(w * 16 + row, 8 * lane)) = hv;
            }
        }
        __syncthreads();

        // ---- 4 iterations of 64 kt, barrier-free ----
        for (int it = 0; it < 4; ++it) {
            const int ktl = it * 64;
            const int ktg = ss * 256 + ktl;

            // K frags direct from global (L1/L2-hot), swapped QK^T: S[kt][q]
            f16x8 ka[4][2];
            #pragma unroll
            for (int cf = 0; cf < 4; ++cf)
                #pragma unroll
                for (int kf = 0; kf < 2; ++kf)
                    ka[cf][kf] = *reinterpret_cast<const f16x8*>(
                        Kp + (size_t)(ktg + cf * 16 + lr) * DH + kf * 32 + lg * 8);
            f32x4 sc[4] = {};
            #pragma unroll
            for (int cf = 0; cf < 4; ++cf)
                #pragma unroll
                for (int kf = 0; kf < 2; ++kf)
                    sc[cf] = __builtin_amdgcn_mfma_f32_16x16x32_f16(
                        ka[cf][kf], qfr[kf], sc[cf], 0, 0, 0);

            // sv = sc*scale*log2e + pbL(block-local q-row = w*16+lr) + mask*log2e
            float sv[4][4];
            #pragma unroll
            for (int cf = 0; cf < 4; ++cf) {
                f16x4 pq = *reinterpret_cast<const f16x4*>(
                    pbB + SWZB(w * 16 + lr, (ktl + cf * 16 + lg * 4) * 2));
                f32x4 mk = *(const f32x4*)(mrow + ktg + cf * 16 + lg * 4);
                #pragma unroll
                for (int r = 0; r < 4; ++r)
                    sv[cf][r] = sc[cf][r] * 0.18033688f + (float)pq[r] + mk[r] * L2E;
            }

            // online softmax: q-row lr lane-local over 16 values, xor 16/32
            float t = sv[0][0];
            #pragma unroll
            for (int cf = 0; cf < 4; ++cf)
                #pragma unroll
                for (int r = 0; r < 4; ++r) t = fmaxf(t, sv[cf][r]);
            t = fmaxf(t, __shfl_xor(t, 16));
            t = fmaxf(t, __shfl_xor(t, 32));
            float mn = fmaxf(m_r, t);
            float sscale = exp2f(m_r - mn);
            m_r = mn;
            float rs = 0.f;
            #pragma unroll
            for (int cf = 0; cf < 4; ++cf) {
                f16x4 pv;
                #pragma unroll
                for (int r = 0; r < 4; ++r) {
                    float p = exp2f(sv[cf][r] - mn);
                    rs += p;
                    pv[r] = (_Float16)p;
                }
                *reinterpret_cast<f16x4*>(
                    Pw + ((lr * 128 + cf * 32 + lg * 8) ^ ((lr & 7) << 4))) = pv;
            }
            rs += __shfl_xor(rs, 16);
            rs += __shfl_xor(rs, 32);
            l_r = l_r * sscale + rs;
            f32x4 scv = {__shfl(sscale, lg * 4 + 0), __shfl(sscale, lg * 4 + 1),
                         __shfl(sscale, lg * 4 + 2), __shfl(sscale, lg * 4 + 3)};
            #pragma unroll
            for (int cf = 0; cf < 4; ++cf) oacc[cf] *= scv;

            // PV: A = P (wave-private LDS round-trip), B = V^T direct
            #pragma unroll
            for (int kf = 0; kf < 2; ++kf) {
                f16x8 pa = *reinterpret_cast<const f16x8*>(
                    Pw + ((lr * 128 + kf * 64 + lg * 16) ^ ((lr & 7) << 4)));
                #pragma unroll
                for (int cf = 0; cf < 4; ++cf) {
                    f16x8 vb = *reinterpret_cast<const f16x8*>(
                        VTp + (size_t)(cf * 16 + lr) * SEQ + ktg + kf * 32 + lg * 8);
                    oacc[cf] = __builtin_amdgcn_mfma_f32_16x16x32_f16(
                        pa, vb, oacc[cf], 0, 0, 0);
                }
            }
        }
    }

    // epilogue: normalize and write ctx[b, s, h*64+d] fp16
    float linv = 1.0f / l_r;
    f32x4 iv = {__shfl(linv, lg * 4 + 0), __shfl(linv, lg * 4 + 1),
                __shfl(linv, lg * 4 + 2), __shfl(linv, lg * 4 + 3)};
    #pragma unroll
    for (int r = 0; r < 4; ++r) {
        int grow = q0 + w * 16 + lg * 4 + r;
        #pragma unroll
        for (int cf = 0; cf < 4; ++cf)
            ctx[((size_t)b * SEQ + grow) * DM + h * DH + cf * 16 + lr] =
                (_Float16)(oacc[cf][r] * iv[r]);
    }
}

extern "C" void kernel_launch(void* const* d_in, const int* in_sizes, int n_in,
                              void* d_out, int out_size, void* d_ws, size_t ws_size,
                              hipStream_t stream) {
    const float* X    = (const float*)d_in[0];
    const float* mask = (const float*)d_in[1];
    const float* pb   = (const float*)d_in[2];
    const float* Wq   = (const float*)d_in[3];
    const float* bq   = (const float*)d_in[4];
    const float* Wk   = (const float*)d_in[5];
    const float* bk   = (const float*)d_in[6];
    const float* Wv   = (const float*)d_in[7];
    const float* bv   = (const float*)d_in[8];
    const float* Wo   = (const float*)d_in[9];
    const float* bo   = (const float*)d_in[10];
    float* out = (float*)d_out;

    _Float16* Xh   = (_Float16*)d_ws;              // 3145728 f16
    _Float16* Wall = Xh + 3145728;                 // 4 * 589824 f16
    _Float16* QK   = Wall + 4 * 589824;            // Q,K slabs: 2 * 3145728
    _Float16* VT   = QK + 2 * 3145728;             // V^T: 3145728
    _Float16* ctx  = VT + 3145728;                 // 3145728

    cast_kernel<<<2688, 256, 0, stream>>>(X, Wq, Wk, Wv, Wo, Xh, Wall);
    gemm_kernel<<<dim3(32, 6, 3), 256, 0, stream>>>(
        Xh, Wall, bq, bk, bv, QK, VT, nullptr, 0);
    attn_kernel<<<768, 256, 0, stream>>>(
        QK, QK + 3145728, VT, pb, mask, ctx);
    gemm_kernel<<<dim3(32, 6, 1), 256, 0, stream>>>(
        ctx, Wall + 3 * 589824, bo, bo, bo, nullptr, nullptr, out, 1);
}

// Round 9
// 191.549 us; speedup vs baseline: 1.5985x; 1.4991x over previous
//
#include <hip/hip_runtime.h>

typedef _Float16 f16x8 __attribute__((ext_vector_type(8)));
typedef _Float16 f16x4 __attribute__((ext_vector_type(4)));
typedef float f32x4 __attribute__((ext_vector_type(4)));

#define NH 12
#define SEQ 2048
#define DM 768
#define DH 64

// ---------------- cast fp32 -> fp16 (X and the 4 weight matrices) --------
__global__ __launch_bounds__(256) void cast_kernel(
    const float* __restrict__ X, const float* __restrict__ Wq,
    const float* __restrict__ Wk, const float* __restrict__ Wv,
    const float* __restrict__ Wo, _Float16* __restrict__ Xh,
    _Float16* __restrict__ Wall)
{
    size_t base = ((size_t)blockIdx.x * 256 + threadIdx.x) * 8;
    const size_t NX = 3145728, NW = 589824, TOT = NX + 4 * NW;
    if (base >= TOT) return;
    const float* src;
    _Float16* dst;
    if (base < NX) { src = X + base; dst = Xh + base; }
    else {
        size_t r = base - NX;
        int w = (int)(r / NW);
        size_t o = r - (size_t)w * NW;
        src = (w == 0 ? Wq : w == 1 ? Wk : w == 2 ? Wv : Wo) + o;
        dst = Wall + r;
    }
    float4 a = *reinterpret_cast<const float4*>(src);
    float4 b = *reinterpret_cast<const float4*>(src + 4);
    f16x8 h;
    h[0] = (_Float16)a.x; h[1] = (_Float16)a.y; h[2] = (_Float16)a.z; h[3] = (_Float16)a.w;
    h[4] = (_Float16)b.x; h[5] = (_Float16)b.y; h[6] = (_Float16)b.z; h[7] = (_Float16)b.w;
    *reinterpret_cast<f16x8*>(dst) = h;
}

// ---------------- GEMM: out = A[4096x768] @ W^T + bias ------------------
// z=0 -> Q slab, z=1 -> K slab ([b,h,s,d]); z=2 -> V^T ([b,h,d,s]).
// is_out==1: fp32 d_out + bias.
__global__ __launch_bounds__(256) void gemm_kernel(
    const _Float16* __restrict__ A,
    const _Float16* __restrict__ Wbase,
    const float* __restrict__ b0, const float* __restrict__ b1,
    const float* __restrict__ b2,
    _Float16* __restrict__ outQKV, _Float16* __restrict__ outVT,
    float* __restrict__ outF32, int is_out)
{
    __shared__ _Float16 Asm[128 * 64];
    __shared__ _Float16 Bsm[128 * 64];
    const int tid = threadIdx.x;
    const int m0 = blockIdx.x * 128, n0 = blockIdx.y * 128, z = blockIdx.z;
    const _Float16* Wp = Wbase + (size_t)z * 589824;
    const float* bias = (z == 0) ? b0 : (z == 1 ? b1 : b2);
    const int w = tid >> 6, lane = tid & 63, lr = lane & 15, lg = lane >> 4;
    const int wm = w >> 1, wn = w & 1;

    f32x4 acc[4][4] = {};
    for (int kt = 0; kt < 12; ++kt) {
        __syncthreads();
        #pragma unroll
        for (int i = 0; i < 4; ++i) {
            int c = tid + i * 256;
            int row = c >> 3, col = (c & 7) * 8;
            int sw = (row & 7) << 4;
            f16x8 av = *reinterpret_cast<const f16x8*>(A + (size_t)(m0 + row) * 768 + kt * 64 + col);
            *reinterpret_cast<f16x8*>((char*)Asm + ((row * 128 + col * 2) ^ sw)) = av;
            f16x8 bv = *reinterpret_cast<const f16x8*>(Wp + (size_t)(n0 + row) * 768 + kt * 64 + col);
            *reinterpret_cast<f16x8*>((char*)Bsm + ((row * 128 + col * 2) ^ sw)) = bv;
        }
        __syncthreads();
        #pragma unroll
        for (int kf = 0; kf < 2; ++kf) {
            f16x8 af[4], bf[4];
            #pragma unroll
            for (int mi = 0; mi < 4; ++mi) {
                int row = wm * 64 + mi * 16 + lr;
                af[mi] = *reinterpret_cast<const f16x8*>(
                    (char*)Asm + ((row * 128 + kf * 64 + lg * 16) ^ ((row & 7) << 4)));
            }
            #pragma unroll
            for (int nj = 0; nj < 4; ++nj) {
                int row = wn * 64 + nj * 16 + lr;
                bf[nj] = *reinterpret_cast<const f16x8*>(
                    (char*)Bsm + ((row * 128 + kf * 64 + lg * 16) ^ ((row & 7) << 4)));
            }
            #pragma unroll
            for (int mi = 0; mi < 4; ++mi)
                #pragma unroll
                for (int nj = 0; nj < 4; ++nj)
                    acc[mi][nj] = __builtin_amdgcn_mfma_f32_16x16x32_f16(
                        af[mi], bf[nj], acc[mi][nj], 0, 0, 0);
        }
    }
    #pragma unroll
    for (int mi = 0; mi < 4; ++mi) {
        #pragma unroll
        for (int nj = 0; nj < 4; ++nj) {
            #pragma unroll
            for (int r = 0; r < 4; ++r) {
                int gm = m0 + wm * 64 + mi * 16 + lg * 4 + r;
                int gn = n0 + wn * 64 + nj * 16 + lr;
                float v = acc[mi][nj][r] + bias[gn];
                if (!is_out) {
                    int bb = gm >> 11, s = gm & 2047, hh = gn >> 6, dd = gn & 63;
                    if (z == 2)
                        outVT[(((size_t)bb * NH + hh) * DH + dd) * SEQ + s] = (_Float16)v;
                    else
                        outQKV[(size_t)z * 3145728 +
                               ((((size_t)bb * NH + hh) * SEQ + s) * DH + dd)] = (_Float16)v;
                } else {
                    outF32[(size_t)gm * 768 + gn] = v;
                }
            }
        }
    }
}

// ---------------- flash attention, batch-shared pb -----------------------
// Block = (h, 32 q-rows) x BOTH batches. 4 waves: w={0,1} -> b=0,
// w={2,3} -> b=1; wave handles 16 q-rows (wl = w&1 selects the 16-row half).
// Waves 0/2 and 1/3 read IDENTICAL pb addresses (pb has no batch index) ->
// the second batch-group's loads hit L1/L2, halving chip-wide pb L2-miss
// bytes. Swapped QK^T (S[kt][q], q lane-local softmax); K/V for both
// batches staged in LDS with one-tile-ahead register prefetch (r3 inner
// structure, the measured-best). K-tile=64, 32 iterations, no split-K.
__global__ __launch_bounds__(256, 3) void attn_kernel(
    const _Float16* __restrict__ Qh, const _Float16* __restrict__ Kh,
    const _Float16* __restrict__ VTg, const float* __restrict__ pb,
    const float* __restrict__ mask, _Float16* __restrict__ ctx)
{
    __shared__ _Float16 Kl[2 * 64 * 64];  // per-batch [kt][d], swizzled (8KB each)
    __shared__ _Float16 Vt[2 * 64 * 64];  // per-batch [d][kt], swizzled
    __shared__ _Float16 Pl[4 * 16 * 64];  // per-wave P tile
    const int tid = threadIdx.x, w = tid >> 6, lane = tid & 63;
    const int lr = lane & 15, lg = lane >> 4;
    const int bsel = w >> 1, wl = w & 1;
    // XCD-aware decode: 768 blocks = 8 XCD * 96; g -> (h, q0)
    const int lin = blockIdx.x;
    const int g = (lin & 7) * 96 + (lin >> 3);
    const int h = g >> 6;
    const int q0 = (g & 63) << 5;          // 32 q-rows per block
    const size_t headoff = ((size_t)bsel * NH + h) * SEQ * DH;
    const _Float16* Qp = Qh + headoff;
    const _Float16* Kp0 = Kh + (size_t)h * SEQ * DH;            // b=0
    const _Float16* Kp1 = Kh + (size_t)(NH + h) * SEQ * DH;     // b=1
    const _Float16* VTp0 = VTg + (size_t)h * SEQ * DH;
    const _Float16* VTp1 = VTg + (size_t)(NH + h) * SEQ * DH;
    const float L2E = 1.44269504f;

    // Q B-frags (q = lr within the wave's 16 rows)
    f16x8 qfr[2];
    #pragma unroll
    for (int kf = 0; kf < 2; ++kf)
        qfr[kf] = *reinterpret_cast<const f16x8*>(
            Qp + (size_t)(q0 + wl * 16 + lr) * DH + kf * 32 + lg * 8);

    // pb row pointer: NO batch term — waves (w, w+2) share these addresses
    const float* pbq = pb + (size_t)h * SEQ * SEQ + (size_t)(q0 + wl * 16 + lr) * SEQ;
    const float* mrow = mask + (size_t)bsel * SEQ;

    f32x4 oacc[4] = {};
    float m_r = -3.0e38f, l_r = 0.f;
    char* Pw = (char*)Pl + w * 2048;
    char* KlB = (char*)Kl + bsel * 8192;   // this wave-group's K tile
    char* VtB = (char*)Vt + bsel * 8192;   // this wave-group's V^T tile

    const int c0 = tid, c1 = tid + 256;
    const int row0 = c0 >> 3, col0 = (c0 & 7) << 3;
    const int row1 = c1 >> 3, col1 = (c1 & 7) << 3;
    f16x8 kn[2][2], vn[2][2];

    // prologue: stage tile 0 for both batches; pb tile 0 into regs
    kn[0][0] = *reinterpret_cast<const f16x8*>(Kp0 + (size_t)row0 * DH + col0);
    kn[0][1] = *reinterpret_cast<const f16x8*>(Kp0 + (size_t)row1 * DH + col1);
    kn[1][0] = *reinterpret_cast<const f16x8*>(Kp1 + (size_t)row0 * DH + col0);
    kn[1][1] = *reinterpret_cast<const f16x8*>(Kp1 + (size_t)row1 * DH + col1);
    vn[0][0] = *reinterpret_cast<const f16x8*>(VTp0 + (size_t)row0 * SEQ + col0);
    vn[0][1] = *reinterpret_cast<const f16x8*>(VTp0 + (size_t)row1 * SEQ + col1);
    vn[1][0] = *reinterpret_cast<const f16x8*>(VTp1 + (size_t)row0 * SEQ + col0);
    vn[1][1] = *reinterpret_cast<const f16x8*>(VTp1 + (size_t)row1 * SEQ + col1);
    f32x4 pbc[4];
    #pragma unroll
    for (int cf = 0; cf < 4; ++cf) {
        f32x4 mk = *reinterpret_cast<const f32x4*>(mrow + cf * 16 + lg * 4);
        pbc[cf] = (*reinterpret_cast<const f32x4*>(pbq + cf * 16 + lg * 4) + mk) * L2E;
    }
    #pragma unroll
    for (int bb = 0; bb < 2; ++bb) {
        char* kd = (char*)Kl + bb * 8192;
        char* vd = (char*)Vt + bb * 8192;
        *reinterpret_cast<f16x8*>(kd + ((row0 * 128 + col0 * 2) ^ ((row0 & 7) << 4))) = kn[bb][0];
        *reinterpret_cast<f16x8*>(kd + ((row1 * 128 + col1 * 2) ^ ((row1 & 7) << 4))) = kn[bb][1];
        *reinterpret_cast<f16x8*>(vd + ((row0 * 128 + col0 * 2) ^ ((row0 & 7) << 4))) = vn[bb][0];
        *reinterpret_cast<f16x8*>(vd + ((row1 * 128 + col1 * 2) ^ ((row1 & 7) << 4))) = vn[bb][1];
    }
    __syncthreads();

    for (int kt0 = 0; kt0 < SEQ; kt0 += 64) {
        const int nt = (kt0 + 64 < SEQ) ? kt0 + 64 : kt0;
        // issue next K/V tile loads for both batches (hidden under compute)
        kn[0][0] = *reinterpret_cast<const f16x8*>(Kp0 + (size_t)(nt + row0) * DH + col0);
        kn[0][1] = *reinterpret_cast<const f16x8*>(Kp0 + (size_t)(nt + row1) * DH + col1);
        kn[1][0] = *reinterpret_cast<const f16x8*>(Kp1 + (size_t)(nt + row0) * DH + col0);
        kn[1][1] = *reinterpret_cast<const f16x8*>(Kp1 + (size_t)(nt + row1) * DH + col1);
        vn[0][0] = *reinterpret_cast<const f16x8*>(VTp0 + (size_t)row0 * SEQ + nt + col0);
        vn[0][1] = *reinterpret_cast<const f16x8*>(VTp0 + (size_t)row1 * SEQ + nt + col1);
        vn[1][0] = *reinterpret_cast<const f16x8*>(VTp1 + (size_t)row0 * SEQ + nt + col0);
        vn[1][1] = *reinterpret_cast<const f16x8*>(VTp1 + (size_t)row1 * SEQ + nt + col1);

        // ---- QK^T swapped: S[kt][q] from this batch's K tile ----
        f32x4 sc[4] = {};
        #pragma unroll
        for (int cf = 0; cf < 4; ++cf) {
            #pragma unroll
            for (int kf = 0; kf < 2; ++kf) {
                f16x8 ka = *reinterpret_cast<const f16x8*>(
                    KlB + (((cf * 16 + lr) * 128 + kf * 64 + lg * 16) ^ ((lr & 7) << 4)));
                sc[cf] = __builtin_amdgcn_mfma_f32_16x16x32_f16(ka, qfr[kf], sc[cf], 0, 0, 0);
            }
        }
        #pragma unroll
        for (int cf = 0; cf < 4; ++cf)
            sc[cf] = sc[cf] * 0.18033688f + pbc[cf];

        // issue next pb loads (waves 2,3 duplicate waves 0,1 -> L1 hits)
        f32x4 pbn[4];
        #pragma unroll
        for (int cf = 0; cf < 4; ++cf) {
            f32x4 mk = *reinterpret_cast<const f32x4*>(mrow + nt + cf * 16 + lg * 4);
            pbn[cf] = (*reinterpret_cast<const f32x4*>(pbq + nt + cf * 16 + lg * 4) + mk) * L2E;
        }

        // ---- online softmax: q-row lr lane-local, xor 16/32 ----
        float t = sc[0][0];
        #pragma unroll
        for (int cf = 0; cf < 4; ++cf)
            #pragma unroll
            for (int r = 0; r < 4; ++r) t = fmaxf(t, sc[cf][r]);
        t = fmaxf(t, __shfl_xor(t, 16));
        t = fmaxf(t, __shfl_xor(t, 32));
        float mn = fmaxf(m_r, t);
        float sscale = exp2f(m_r - mn);
        m_r = mn;
        float rs = 0.f;
        #pragma unroll
        for (int cf = 0; cf < 4; ++cf) {
            f16x4 pv;
            #pragma unroll
            for (int r = 0; r < 4; ++r) {
                float p = exp2f(sc[cf][r] - mn);
                rs += p;
                pv[r] = (_Float16)p;
            }
            *reinterpret_cast<f16x4*>(
                Pw + ((lr * 128 + cf * 32 + lg * 8) ^ ((lr & 7) << 4))) = pv;
        }
        rs += __shfl_xor(rs, 16);
        rs += __shfl_xor(rs, 32);
        l_r = l_r * sscale + rs;
        f32x4 scv = {__shfl(sscale, lg * 4 + 0), __shfl(sscale, lg * 4 + 1),
                     __shfl(sscale, lg * 4 + 2), __shfl(sscale, lg * 4 + 3)};
        #pragma unroll
        for (int cf = 0; cf < 4; ++cf) oacc[cf] *= scv;

        // ---- PV: A = P (wave-private LDS round-trip), B = this batch's V^T
        #pragma unroll
        for (int kf = 0; kf < 2; ++kf) {
            f16x8 pa = *reinterpret_cast<const f16x8*>(
                Pw + ((lr * 128 + kf * 64 + lg * 16) ^ ((lr & 7) << 4)));
            #pragma unroll
            for (int cf = 0; cf < 4; ++cf) {
                f16x8 vb = *reinterpret_cast<const f16x8*>(
                    VtB + (((cf * 16 + lr) * 128 + kf * 64 + lg * 16) ^ ((lr & 7) << 4)));
                oacc[cf] = __builtin_amdgcn_mfma_f32_16x16x32_f16(pa, vb, oacc[cf], 0, 0, 0);
            }
        }

        // ---- commit prefetched tiles ----
        __syncthreads();
        #pragma unroll
        for (int bb = 0; bb < 2; ++bb) {
            char* kd = (char*)Kl + bb * 8192;
            char* vd = (char*)Vt + bb * 8192;
            *reinterpret_cast<f16x8*>(kd + ((row0 * 128 + col0 * 2) ^ ((row0 & 7) << 4))) = kn[bb][0];
            *reinterpret_cast<f16x8*>(kd + ((row1 * 128 + col1 * 2) ^ ((row1 & 7) << 4))) = kn[bb][1];
            *reinterpret_cast<f16x8*>(vd + ((row0 * 128 + col0 * 2) ^ ((row0 & 7) << 4))) = vn[bb][0];
            *reinterpret_cast<f16x8*>(vd + ((row1 * 128 + col1 * 2) ^ ((row1 & 7) << 4))) = vn[bb][1];
        }
        #pragma unroll
        for (int cf = 0; cf < 4; ++cf) pbc[cf] = pbn[cf];
        __syncthreads();
    }

    // epilogue: normalize and write ctx[bsel, s, h*64+d] fp16
    float linv = 1.0f / l_r;
    f32x4 iv = {__shfl(linv, lg * 4 + 0), __shfl(linv, lg * 4 + 1),
                __shfl(linv, lg * 4 + 2), __shfl(linv, lg * 4 + 3)};
    #pragma unroll
    for (int r = 0; r < 4; ++r) {
        int grow = q0 + wl * 16 + lg * 4 + r;
        #pragma unroll
        for (int cf = 0; cf < 4; ++cf)
            ctx[((size_t)bsel * SEQ + grow) * DM + h * DH + cf * 16 + lr] =
                (_Float16)(oacc[cf][r] * iv[r]);
    }
}

extern "C" void kernel_launch(void* const* d_in, const int* in_sizes, int n_in,
                              void* d_out, int out_size, void* d_ws, size_t ws_size,
                              hipStream_t stream) {
    const float* X    = (const float*)d_in[0];
    const float* mask = (const float*)d_in[1];
    const float* pb   = (const float*)d_in[2];
    const float* Wq   = (const float*)d_in[3];
    const float* bq   = (const float*)d_in[4];
    const float* Wk   = (const float*)d_in[5];
    const float* bk   = (const float*)d_in[6];
    const float* Wv   = (const float*)d_in[7];
    const float* bv   = (const float*)d_in[8];
    const float* Wo   = (const float*)d_in[9];
    const float* bo   = (const float*)d_in[10];
    float* out = (float*)d_out;

    _Float16* Xh   = (_Float16*)d_ws;              // 3145728 f16
    _Float16* Wall = Xh + 3145728;                 // 4 * 589824 f16
    _Float16* QK   = Wall + 4 * 589824;            // Q,K slabs: 2 * 3145728
    _Float16* VT   = QK + 2 * 3145728;             // V^T: 3145728
    _Float16* ctx  = VT + 3145728;                 // 3145728

    cast_kernel<<<2688, 256, 0, stream>>>(X, Wq, Wk, Wv, Wo, Xh, Wall);
    gemm_kernel<<<dim3(32, 6, 3), 256, 0, stream>>>(
        Xh, Wall, bq, bk, bv, QK, VT, nullptr, 0);
    attn_kernel<<<768, 256, 0, stream>>>(
        QK, QK + 3145728, VT, pb, mask, ctx);
    gemm_kernel<<<dim3(32, 6, 1), 256, 0, stream>>>(
        ctx, Wall + 3 * 589824, bo, bo, bo, nullptr, nullptr, out, 1);
}